// Round 1
// baseline (156.526 us; speedup 1.0000x reference)
//
#include <hip/hip_runtime.h>

// BinStats: per-channel searchsorted histogram.
//   x:(B=64, C=512, H=28, W=28) f32, bin_edges:(512,11), feature_ranges:(512,1),
//   bin_counts:(512,10). out[c][j] = bin_counts[c][j] + #{elements of channel c in bin j}
//   where bin j = searchsorted(inner_edges(9), x/range, side='left').
//
// Design (memory-bound, 102.8 MB read):
//  - one block per channel (512 blocks x 1024 threads): edges are wave-uniform,
//    per-thread register counters stay channel-pure, no global atomics needed.
//  - counters t[j] = count(x > edge_j * range): searchsorted-left folded into
//    9 branchless compare-adds; hist[j] = t[j-1] - t[j] by sortedness of edges.
//  - range folded into edges once per block (e_j*r < x  <=>  e_j < x/r, r>0).
//  - float4 loads: 784 floats per (b,c) slab => each float4 is channel-pure.
//  - R1: 2x float4 per lane per iteration (32B/lane) -> halves loop/index
//    overhead per byte, doubles loads in flight. 12544 = 6*2048 + 256:
//    6 paired iterations + a tid<256 tail.

#define N_CH    512
#define HW      784            // 28*28
#define NB      64             // batch
#define F4_PER_SLAB 196        // HW/4
#define NF4     (NB * F4_PER_SLAB)  // float4s per channel = 12544
#define BLK     1024
#define CH_STRIDE_F4 (N_CH * F4_PER_SLAB)  // float4 stride between batches
#define TOTAL_PER_CH (NB * HW) // 50176
#define MAIN_END 12288         // 6 * 2048

__global__ __launch_bounds__(BLK, 2) void binstats_kernel(
    const float* __restrict__ x,
    const float* __restrict__ bin_edges,      // (512, 11)
    const float* __restrict__ feature_ranges, // (512,)
    const float* __restrict__ bin_counts,     // (512, 10)
    float* __restrict__ out)                  // (512, 10)
{
    const int c   = blockIdx.x;
    const int tid = threadIdx.x;

    __shared__ unsigned t_sh[9];
    if (tid < 9) t_sh[tid] = 0u;

    // Per-channel scaled inner edges (uniform across block -> s_load + SGPRs).
    const float r = feature_ranges[c];
    float e[9];
#pragma unroll
    for (int j = 0; j < 9; ++j) e[j] = bin_edges[c * 11 + 1 + j] * r;

    __syncthreads();

    unsigned t[9];
#pragma unroll
    for (int j = 0; j < 9; ++j) t[j] = 0u;

    const float4* xf4 = (const float4*)x;

    // Main: 6 iterations, two float4s per lane per iteration.
    for (int i = tid; i < MAIN_END; i += 2 * BLK) {
        const int ia = i;
        const int ib = i + BLK;
        const int ba = ia / F4_PER_SLAB;          // magic-mul, constant divisor
        const int pa = ia - ba * F4_PER_SLAB;
        const int bb = ib / F4_PER_SLAB;
        const int pb = ib - bb * F4_PER_SLAB;
        // Issue both loads before the compare chains (MLP).
        const float4 va = xf4[ba * CH_STRIDE_F4 + c * F4_PER_SLAB + pa];
        const float4 vb = xf4[bb * CH_STRIDE_F4 + c * F4_PER_SLAB + pb];
#pragma unroll
        for (int j = 0; j < 9; ++j) {
            t[j] += (unsigned)(va.x > e[j]);
            t[j] += (unsigned)(va.y > e[j]);
            t[j] += (unsigned)(va.z > e[j]);
            t[j] += (unsigned)(va.w > e[j]);
            t[j] += (unsigned)(vb.x > e[j]);
            t[j] += (unsigned)(vb.y > e[j]);
            t[j] += (unsigned)(vb.z > e[j]);
            t[j] += (unsigned)(vb.w > e[j]);
        }
    }

    // Tail: remaining 256 float4s (indices 12288..12543).
    if (tid < NF4 - MAIN_END) {
        const int i = MAIN_END + tid;
        const int b   = i / F4_PER_SLAB;
        const int pos = i - b * F4_PER_SLAB;
        const float4 v = xf4[b * CH_STRIDE_F4 + c * F4_PER_SLAB + pos];
#pragma unroll
        for (int j = 0; j < 9; ++j) {
            t[j] += (unsigned)(v.x > e[j]);
            t[j] += (unsigned)(v.y > e[j]);
            t[j] += (unsigned)(v.z > e[j]);
            t[j] += (unsigned)(v.w > e[j]);
        }
    }

    // Wave-level reduce (64 lanes), then one LDS atomic per wave per counter.
#pragma unroll
    for (int j = 0; j < 9; ++j) {
        unsigned v = t[j];
        for (int off = 32; off > 0; off >>= 1)
            v += __shfl_down(v, off, 64);
        if ((tid & 63) == 0) atomicAdd(&t_sh[j], v);
    }
    __syncthreads();

    // hist[0] = N - t[0]; hist[j] = t[j-1] - t[j]; hist[9] = t[8]
    if (tid < 10) {
        unsigned h;
        if (tid == 0)       h = (unsigned)TOTAL_PER_CH - t_sh[0];
        else if (tid == 9)  h = t_sh[8];
        else                h = t_sh[tid - 1] - t_sh[tid];
        out[c * 10 + tid] = bin_counts[c * 10 + tid] + (float)h;
    }
}

extern "C" void kernel_launch(void* const* d_in, const int* in_sizes, int n_in,
                              void* d_out, int out_size, void* d_ws, size_t ws_size,
                              hipStream_t stream) {
    const float* x  = (const float*)d_in[0];
    const float* be = (const float*)d_in[1];
    const float* fr = (const float*)d_in[2];
    const float* bc = (const float*)d_in[3];
    float* out = (float*)d_out;

    binstats_kernel<<<N_CH, BLK, 0, stream>>>(x, be, fr, bc, out);
}